// Round 10
// baseline (50.592 us; speedup 1.0000x reference)
//
#include <hip/hip_runtime.h>

#define VOCAB 32000
#define NB 32
#define NS 32
#define NA 512
#define QPB 8              // blocks per (b,s) row
#define VPB (VOCAB / QPB)  // 4000 vocab entries per block
#define V4PB (VPB / 4)     // 1000 float4 slots per block
#define TPB 256
#define NITER ((V4PB + TPB - 1) / TPB)  // 4 (last iter ragged: 232 lanes)

typedef float f32x4 __attribute__((ext_vector_type(4)));
typedef unsigned int u32;
typedef u32 u32x4 __attribute__((ext_vector_type(4)));

// Monotone map float -> u32 so unsigned max == float max (no NaNs in input).
__device__ __forceinline__ u32 fkey(float f) {
    u32 b = __float_as_uint(f);
    return (b & 0x80000000u) ? ~b : (b | 0x80000000u);
}
__device__ __forceinline__ float funkey(u32 k) {
    u32 b = (k & 0x80000000u) ? (k & 0x7FFFFFFFu) : ~k;
    return __uint_as_float(b);
}
#define KEY_NEG_INF 0x007FFFFFu  // fkey(-inf): decodes back to -inf

// One block per (row, vocab-eighth). 16KB LDS -> 8 blocks/CU (wave-capped)
// = 32 waves/CU ~ 100% occupancy, double R9's 46%. After the scatter phase,
// keys are converted to float in LDS once, so the hot loop is load / ds_read
// / fmax / NT-store with no key decode. 4 streaming loads prefetched up
// front for MLP.
__global__ void __launch_bounds__(TPB) fused_kernel(
        const f32x4* __restrict__ dec4,   // (B*S*VOCAB/4)
        const float* __restrict__ att,    // (B,S,A)
        const int* __restrict__ seq,      // (B,A)
        const int* __restrict__ table,    // (SRC_VOCAB)
        f32x4* __restrict__ out4) {
    __shared__ u32 keys[VPB];  // 16 KB
    const int blk = blockIdx.x;
    const int row = blk >> 3;  // b*NS + s
    const int q   = blk & 7;
    const int b   = row >> 5;
    const int lo  = q * VPB;
    const int tid = threadIdx.x;

    const u32x4 initv = {KEY_NEG_INF, KEY_NEG_INF, KEY_NEG_INF, KEY_NEG_INF};
#pragma unroll
    for (int k = 0; k < NITER; ++k) {
        const int i = tid + k * TPB;
        if (i < V4PB) ((u32x4*)keys)[i] = initv;
    }
    __syncthreads();

#pragma unroll
    for (int k = 0; k < NA / TPB; ++k) {
        const int a = tid + k * TPB;
        const int v = table[seq[b * NA + a]] - lo;
        if ((u32)v < (u32)VPB)
            atomicMax(&keys[v], fkey(att[(size_t)row * NA + a]));
    }
    __syncthreads();

    // Convert keys -> float in place (one pass) so the hot loop needs no decode.
#pragma unroll
    for (int k = 0; k < NITER; ++k) {
        const int i = tid + k * TPB;
        if (i < V4PB) {
            const u32x4 kk = ((const u32x4*)keys)[i];
            f32x4 f;
            f.x = funkey(kk.x); f.y = funkey(kk.y);
            f.z = funkey(kk.z); f.w = funkey(kk.w);
            ((f32x4*)keys)[i] = f;
        }
    }
    __syncthreads();

    const size_t base = (size_t)row * (VOCAB / 4) + (size_t)q * V4PB;
    // Prefetch all streaming loads, then compute: guarantees 4 loads in flight.
    f32x4 d[NITER];
#pragma unroll
    for (int k = 0; k < NITER; ++k) {
        const int i = tid + k * TPB;
        if (i < V4PB) d[k] = dec4[base + i];
    }
#pragma unroll
    for (int k = 0; k < NITER; ++k) {
        const int i = tid + k * TPB;
        if (i < V4PB) {
            const f32x4 f = ((const f32x4*)keys)[i];
            f32x4 m;
            m.x = fmaxf(d[k].x, f.x);
            m.y = fmaxf(d[k].y, f.y);
            m.z = fmaxf(d[k].z, f.z);
            m.w = fmaxf(d[k].w, f.w);
            if (q == 0 && i == 0) m.y = 0.0f;  // vocab element 1 of this row
            __builtin_nontemporal_store(m, &out4[base + i]);
        }
    }
}

extern "C" void kernel_launch(void* const* d_in, const int* in_sizes, int n_in,
                              void* d_out, int out_size, void* d_ws, size_t ws_size,
                              hipStream_t stream) {
    const float* decoder_outputs = (const float*)d_in[0];   // (32,32,32000) f32
    const float* attention_scores = (const float*)d_in[1];  // (32,32,512) f32
    const int* input_sequence = (const int*)d_in[2];        // (32,512) i32
    // d_in[3], d_in[4]: repeat_idx / repeat_idx2 — unused by the math
    const int* convert_table = (const int*)d_in[5];         // (50000,) i32
    float* out = (float*)d_out;                             // (32,32,32000) f32

    fused_kernel<<<NB * NS * QPB, TPB, 0, stream>>>(
        (const f32x4*)decoder_outputs, attention_scores,
        input_sequence, convert_table, (f32x4*)out);
}

// Round 11
// 47.266 us; speedup vs baseline: 1.0704x; 1.0704x over previous
//
#include <hip/hip_runtime.h>

#define VOCAB 32000
#define NB 32
#define NS 32
#define NA 512
#define QPB 4              // blocks per (b,s) row
#define VPB (VOCAB / QPB)  // 8000 vocab entries per block
#define V4PB (VPB / 4)     // 2000 float4 slots per block
#define TPB 256
#define NITER ((V4PB + TPB - 1) / TPB)  // 8 (exact: 2000/256 -> ragged)

typedef float f32x4 __attribute__((ext_vector_type(4)));
typedef unsigned int u32;
typedef u32 u32x4 __attribute__((ext_vector_type(4)));

// Monotone map float -> u32 so unsigned max == float max (no NaNs in input).
__device__ __forceinline__ u32 fkey(float f) {
    u32 b = __float_as_uint(f);
    return (b & 0x80000000u) ? ~b : (b | 0x80000000u);
}
__device__ __forceinline__ float funkey(u32 k) {
    u32 b = (k & 0x80000000u) ? (k & 0x7FFFFFFFu) : ~k;
    return __uint_as_float(b);
}
#define KEY_NEG_INF 0x007FFFFFu  // fkey(-inf): decodes back to -inf

// R7 config (best measured: 48.0us) + hoisted key decode + load prefetch.
// One block per (row, vocab-quarter): scatter-max in LDS via ds_max_u32 on
// monotone keys; decode keys->float once; then stream: cached loads (input
// rides the 256MB MALL), fmax vs LDS, NT stores (write stream no-allocate).
__global__ void __launch_bounds__(TPB) fused_kernel(
        const f32x4* __restrict__ dec4,   // (B*S*VOCAB/4)
        const float* __restrict__ att,    // (B,S,A)
        const int* __restrict__ seq,      // (B,A)
        const int* __restrict__ table,    // (SRC_VOCAB)
        f32x4* __restrict__ out4) {
    __shared__ u32 keys[VPB];  // 32 KB
    const int blk = blockIdx.x;
    const int row = blk >> 2;  // b*NS + s
    const int q   = blk & 3;
    const int b   = row >> 5;
    const int lo  = q * VPB;
    const int tid = threadIdx.x;

    const u32x4 initv = {KEY_NEG_INF, KEY_NEG_INF, KEY_NEG_INF, KEY_NEG_INF};
#pragma unroll
    for (int k = 0; k < NITER; ++k) {
        const int i = tid + k * TPB;
        if (i < V4PB) ((u32x4*)keys)[i] = initv;
    }
    __syncthreads();

#pragma unroll
    for (int k = 0; k < NA / TPB; ++k) {
        const int a = tid + k * TPB;
        const int v = table[seq[b * NA + a]] - lo;
        if ((u32)v < (u32)VPB)
            atomicMax(&keys[v], fkey(att[(size_t)row * NA + a]));
    }
    __syncthreads();

    // Decode keys -> float in place once, so the hot loop has no decode chain.
#pragma unroll
    for (int k = 0; k < NITER; ++k) {
        const int i = tid + k * TPB;
        if (i < V4PB) {
            const u32x4 kk = ((const u32x4*)keys)[i];
            f32x4 f;
            f.x = funkey(kk.x); f.y = funkey(kk.y);
            f.z = funkey(kk.z); f.w = funkey(kk.w);
            ((f32x4*)keys)[i] = f;
        }
    }
    __syncthreads();

    const size_t base = (size_t)row * (VOCAB / 4) + (size_t)q * V4PB;
    // Batch the streaming loads ahead of the compute for guaranteed MLP.
    f32x4 d[NITER];
#pragma unroll
    for (int k = 0; k < NITER; ++k) {
        const int i = tid + k * TPB;
        if (i < V4PB) d[k] = dec4[base + i];
    }
#pragma unroll
    for (int k = 0; k < NITER; ++k) {
        const int i = tid + k * TPB;
        if (i < V4PB) {
            const f32x4 f = ((const f32x4*)keys)[i];
            f32x4 m;
            m.x = fmaxf(d[k].x, f.x);
            m.y = fmaxf(d[k].y, f.y);
            m.z = fmaxf(d[k].z, f.z);
            m.w = fmaxf(d[k].w, f.w);
            if (q == 0 && i == 0) m.y = 0.0f;  // vocab element 1 of this row
            __builtin_nontemporal_store(m, &out4[base + i]);
        }
    }
}

extern "C" void kernel_launch(void* const* d_in, const int* in_sizes, int n_in,
                              void* d_out, int out_size, void* d_ws, size_t ws_size,
                              hipStream_t stream) {
    const float* decoder_outputs = (const float*)d_in[0];   // (32,32,32000) f32
    const float* attention_scores = (const float*)d_in[1];  // (32,32,512) f32
    const int* input_sequence = (const int*)d_in[2];        // (32,512) i32
    // d_in[3], d_in[4]: repeat_idx / repeat_idx2 — unused by the math
    const int* convert_table = (const int*)d_in[5];         // (50000,) i32
    float* out = (float*)d_out;                             // (32,32,32000) f32

    fused_kernel<<<NB * NS * QPB, TPB, 0, stream>>>(
        (const f32x4*)decoder_outputs, attention_scores,
        input_sequence, convert_table, (f32x4*)out);
}